// Round 3
// baseline (95.962 us; speedup 1.0000x reference)
//
#include <hip/hip_runtime.h>
#include <hip/hip_bf16.h>

// out[b] = adj @ (x[b] @ W) + bias ; B=64, N=4096, F_IN=F_OUT=32
// R18: FAITHFUL 8-PHASE (m201 template) on the R16-verified geometry.
//   Post-mortem R17: L2-region swizzle cut FETCH 82->65.6MB but dur unchanged
//   -> staging BW not binding. MfmaUtil pinned at 46-48% = the 2-phase
//   structure's documented ceiling (m103 37% vs m201 62%). R16's failure was
//   the COARSE split (lgkm drain before barrier, all stages clustered) that
//   m196 predicts hurts. This round: per K-tile 4 fine phases
//   {ds_read frags | 1-2 stage gloads -> bar -> lgkm0+sched0 -> prio1 8 MFMA
//   prio0 -> bar}, ring-3 LDS (3x48KB), vmcnt(6) ONCE per tile (never 0)
//   before the tile's last barrier. T2 swizzle + T5 setprio retained.
//   Geometry (R16-correct): block 128Mx256N, 8 waves = 2wr x 2nc x 2ks,
//   wave tile 64x128, grid 256 = 1 blk/CU, split-K merge in dead ring LDS.
// Prep unchanged (~33us, near HBM roofline). ws>=50.4MB proven; fallback kept.

#define B_SZ 64
#define N_SZ 4096
#define NT 64
#define STG 49152

typedef __attribute__((ext_vector_type(8))) short bf16x8;
typedef __attribute__((ext_vector_type(4))) float f32x4;
typedef __attribute__((ext_vector_type(8))) unsigned short u16x8;

__device__ __forceinline__ unsigned short f2bf(float f) {
  unsigned int u = __float_as_uint(f);
  u += 0x7fffu + ((u >> 16) & 1u);
  return (unsigned short)(u >> 16);
}

__device__ __forceinline__ void support_body(const float* __restrict__ x,
                                             const float* __restrict__ W,
                                             unsigned short* __restrict__ St,
                                             int gid) {
  const int m = gid & (N_SZ - 1);
  const int b = gid >> 12;
  const float4* xr = (const float4*)(x + (size_t)gid * 32);
  float xv[32];
#pragma unroll
  for (int i = 0; i < 8; ++i) {
    float4 v = xr[i];
    xv[4 * i + 0] = v.x; xv[4 * i + 1] = v.y;
    xv[4 * i + 2] = v.z; xv[4 * i + 3] = v.w;
  }
  const size_t obase = ((size_t)b * 32) * (size_t)N_SZ + m;
#pragma unroll
  for (int o = 0; o < 32; ++o) {
    float acc = 0.f;
#pragma unroll
    for (int f = 0; f < 32; ++f) acc = fmaf(xv[f], W[f * 32 + o], acc);
    St[obase + (size_t)o * N_SZ] = f2bf(acc);
  }
}

__device__ __forceinline__ void cvt_body(const float* __restrict__ a,
                                         unsigned short* __restrict__ o,
                                         size_t idx8) {
  const size_t i = idx8 * 8;
  const float4* p = (const float4*)(a + i);
  float4 v0 = p[0], v1 = p[1];
  u16x8 r;
  r[0] = f2bf(v0.x); r[1] = f2bf(v0.y); r[2] = f2bf(v0.z); r[3] = f2bf(v0.w);
  r[4] = f2bf(v1.x); r[5] = f2bf(v1.y); r[6] = f2bf(v1.z); r[7] = f2bf(v1.w);
  *(u16x8*)(o + i) = r;
}

// ---------------- prep: fused full-adj cvt + support (full path) ------------
__global__ __launch_bounds__(256) void k_prep(const float* __restrict__ x,
                                              const float* __restrict__ adj,
                                              const float* __restrict__ W,
                                              unsigned short* __restrict__ St,
                                              unsigned short* __restrict__ adjB) {
  const int bid = blockIdx.x;
  const int t = threadIdx.x;
  if (bid < 8192) cvt_body(adj, adjB, (size_t)bid * 256 + t);
  else support_body(x, W, St, (bid - 8192) * 256 + t);
}

// fallback-path kernels
__global__ __launch_bounds__(256) void k_support(const float* __restrict__ x,
                                                 const float* __restrict__ W,
                                                 unsigned short* __restrict__ St) {
  support_body(x, W, St, blockIdx.x * 256 + threadIdx.x);
}
__global__ __launch_bounds__(256) void k_cvt(const float* __restrict__ a,
                                             unsigned short* __restrict__ o) {
  cvt_body(a, o, (size_t)blockIdx.x * 256 + threadIdx.x);
}

// -- GEMM: 128Mx256N, 8 waves (2M x 2N x 2KS), ring-3, 4-phase/K-tile --------
#define GLOAD16(gp, lp)                                                        \
  __builtin_amdgcn_global_load_lds(                                            \
      (const __attribute__((address_space(1))) void*)(gp),                     \
      (__attribute__((address_space(3))) void*)(lp), 16, 0, 0)
#define PRIO1() __builtin_amdgcn_s_setprio(1)
#define PRIO0() __builtin_amdgcn_s_setprio(0)
#define VMW(N_) asm volatile("s_waitcnt vmcnt(" #N_ ")" ::: "memory")
#define LGKM0() asm volatile("s_waitcnt lgkmcnt(0)" ::: "memory")
#define BAR() asm volatile("s_barrier" ::: "memory")
#define SCHED0() __builtin_amdgcn_sched_barrier(0)

__global__ __launch_bounds__(512, 2) void k_gemm8p(const unsigned short* __restrict__ Ab,
                                                   const unsigned short* __restrict__ Bm,
                                                   const float* __restrict__ bias,
                                                   float* __restrict__ out,
                                                   int nbm, int rowoff) {
  __shared__ __attribute__((aligned(16))) char SM[147456];  // 3 x 48KB ring
  const int t = threadIdx.x;
  const int wg = blockIdx.x;
  const int xcd = wg & 7;
  const int idx = wg >> 3;
  // L2-region mapping (R17-proven traffic win): XCD owns an M-strip.
  const int bm0 = (xcd * nbm + (idx >> 3)) << 7;  // 128-row panel
  const int bn0 = (idx & 7) << 8;                 // 256-col panel
  const int lane = t & 63;
  const int wid = t >> 6;          // 0..7
  const int wr = wid & 1;          // M-half (64 rows)
  const int nc = (wid >> 1) & 1;   // N-half (128 cols)
  const int ks = wid >> 2;         // split-K team: kk-half of BK=64

  f32x4 acc[4][8];
#pragma unroll
  for (int i = 0; i < 4; ++i)
#pragma unroll
    for (int j = 0; j < 8; ++j) acc[i][j] = (f32x4){0.f, 0.f, 0.f, 0.f};

  // staging: 6 gloads/tile (A 2 + B 4), each 512thr x 16B = 8KB = 64 rows
  const int srow = t >> 3;   // 0..63
  const int as = t & 7;
  const int swz = (as ^ (srow & 7)) << 4;  // inverse-swizzled source (rule #21)
  const size_t a_s0 = ((size_t)(bm0 + srow) << 13) + (size_t)swz;
  const size_t b_s0 = ((size_t)(bn0 + srow) << 13) + (size_t)swz;
  const int t16 = t * 16;
  const char* A8 = (const char*)Ab;
  const char* B8 = (const char*)Bm;

  // fragment LDS byte offsets (kk = ks per team; XOR swizzle, proven)
  const int cbase = (ks * 64 + ((lane >> 4) << 4)) ^ ((lane & 7) << 4);
  int aoff[4], boff[8];
#pragma unroll
  for (int mi = 0; mi < 4; ++mi)
    aoff[mi] = (wr * 64 + mi * 16 + (lane & 15)) * 128 + cbase;
#pragma unroll
  for (int ni = 0; ni < 8; ++ni)
    boff[ni] = 16384 + (nc * 128 + ni * 16 + (lane & 15)) * 128 + cbase;

#define STAGEALL(KT_, LOFF_)                                                   \
  do {                                                                         \
    const size_t kb = (size_t)(KT_) << 7;                                      \
    GLOAD16(A8 + a_s0 + kb,           SM + (LOFF_) + t16);                     \
    GLOAD16(A8 + a_s0 + 524288 + kb,  SM + (LOFF_) + 8192 + t16);              \
    GLOAD16(B8 + b_s0 + kb,           SM + (LOFF_) + 16384 + t16);             \
    GLOAD16(B8 + b_s0 + 524288 + kb,  SM + (LOFF_) + 24576 + t16);             \
    GLOAD16(B8 + b_s0 + 1048576 + kb, SM + (LOFF_) + 32768 + t16);             \
    GLOAD16(B8 + b_s0 + 1572864 + kb, SM + (LOFF_) + 40960 + t16);             \
  } while (0)

#define MFMA2(N0_, N1_)                                                        \
  do {                                                                         \
    _Pragma("unroll") for (int mi = 0; mi < 4; ++mi) {                         \
      acc[mi][N0_] = __builtin_amdgcn_mfma_f32_16x16x32_bf16(                  \
          a[mi], b[N0_], acc[mi][N0_], 0, 0, 0);                               \
      acc[mi][N1_] = __builtin_amdgcn_mfma_f32_16x16x32_bf16(                  \
          a[mi], b[N1_], acc[mi][N1_], 0, 0, 0);                               \
    }                                                                          \
  } while (0)

  // One K-tile = 4 fine phases (m201 template): {ds ∥ gload, bar, lgkm0,
  // prio1 MFMA prio0, bar}. VMN_ = tile-boundary counted vmcnt, before the
  // last barrier so the barrier publishes every wave's drain block-wide.
#define TILE(T_, CUR_, NXT_, DOST_, VMN_)                                      \
  do {                                                                         \
    const char* Lc = SM + (CUR_) * STG;                                        \
    char* Ln = SM + (NXT_) * STG;                                              \
    const size_t kb = ((size_t)(T_) + 2) << 7;                                 \
    (void)Ln; (void)kb;                                                        \
    bf16x8 a[4], b[8];                                                         \
    /* P0: a0-3,b0,b1 | g0,g1 */                                               \
    _Pragma("unroll") for (int mi = 0; mi < 4; ++mi)                           \
        a[mi] = *(const bf16x8*)(Lc + aoff[mi]);                               \
    b[0] = *(const bf16x8*)(Lc + boff[0]);                                     \
    b[1] = *(const bf16x8*)(Lc + boff[1]);                                     \
    if (DOST_) {                                                               \
      GLOAD16(A8 + a_s0 + kb, Ln + t16);                                       \
      GLOAD16(A8 + a_s0 + 524288 + kb, Ln + 8192 + t16);                       \
    }                                                                          \
    BAR(); LGKM0(); SCHED0(); PRIO1(); MFMA2(0, 1); PRIO0(); BAR();            \
    /* P1: b2,b3 | g2 */                                                       \
    b[2] = *(const bf16x8*)(Lc + boff[2]);                                     \
    b[3] = *(const bf16x8*)(Lc + boff[3]);                                     \
    if (DOST_) GLOAD16(B8 + b_s0 + kb, Ln + 16384 + t16);                      \
    BAR(); LGKM0(); SCHED0(); PRIO1(); MFMA2(2, 3); PRIO0(); BAR();            \
    /* P2: b4,b5 | g3 */                                                       \
    b[4] = *(const bf16x8*)(Lc + boff[4]);                                     \
    b[5] = *(const bf16x8*)(Lc + boff[5]);                                     \
    if (DOST_) GLOAD16(B8 + b_s0 + 524288 + kb, Ln + 24576 + t16);             \
    BAR(); LGKM0(); SCHED0(); PRIO1(); MFMA2(4, 5); PRIO0(); BAR();            \
    /* P3: b6,b7 | g4,g5 | tile-boundary counted vmcnt */                      \
    b[6] = *(const bf16x8*)(Lc + boff[6]);                                     \
    b[7] = *(const bf16x8*)(Lc + boff[7]);                                     \
    if (DOST_) {                                                               \
      GLOAD16(B8 + b_s0 + 1048576 + kb, Ln + 32768 + t16);                     \
      GLOAD16(B8 + b_s0 + 1572864 + kb, Ln + 40960 + t16);                     \
    }                                                                          \
    BAR(); LGKM0(); SCHED0(); PRIO1(); MFMA2(6, 7); PRIO0();                   \
    VMN_;                                                                      \
    BAR();                                                                     \
  } while (0)

  // prologue: tiles 0,1 into bufs 0,1; wait tile 0 (6 of tile 1 in flight)
  STAGEALL(0, 0);
  STAGEALL(1, STG);
  VMW(6);
  BAR();

#pragma clang loop unroll(disable)
  for (int t0 = 0; t0 < 60; t0 += 3) {   // tiles 0..59, static ring phase
    TILE(t0 + 0, 0, 2, 1, VMW(6));
    TILE(t0 + 1, 1, 0, 1, VMW(6));
    TILE(t0 + 2, 2, 1, 1, VMW(6));
  }
  TILE(60, 0, 2, 1, VMW(6));
  TILE(61, 1, 0, 1, VMW(6));   // stages tile 63; end: tile 62 landed
  TILE(62, 2, 1, 0, VMW(0));   // no stage; end: tile 63 landed
  TILE(63, 0, 1, 0, );         // last tile

  // ------- split-K merge through LDS (ring is dead now; 4 x 32KB regions) ---
  if (ks == 1) {
    char* mb = SM + ((wid & 3) << 15);
#pragma unroll
    for (int mi = 0; mi < 4; ++mi)
#pragma unroll
      for (int ni = 0; ni < 8; ++ni)
        *(f32x4*)(mb + (((mi * 8 + ni) << 6) + lane) * 16) = acc[mi][ni];
  }
  __syncthreads();
  if (ks == 0) {
    char* mb = SM + ((wid & 3) << 15);
#pragma unroll
    for (int mi = 0; mi < 4; ++mi)
#pragma unroll
      for (int ni = 0; ni < 8; ++ni)
        acc[mi][ni] += *(const f32x4*)(mb + (((mi * 8 + ni) << 6) + lane) * 16);
    // ---- epilogue: C/D layout col=lane&15, row=(lane>>4)*4+q (proven) ----
    const float blo = bias[lane & 15];
    const float bhi = bias[(lane & 15) + 16];
#pragma unroll
    for (int mi = 0; mi < 4; ++mi) {
#pragma unroll
      for (int ni = 0; ni < 8; ++ni) {
        const float badd = (ni & 1) ? bhi : blo;
#pragma unroll
        for (int q = 0; q < 4; ++q) {
          const int n = rowoff + bm0 + wr * 64 + mi * 16 + ((lane >> 4) << 2) + q;
          const int cidx = bn0 + nc * 128 + ni * 16 + (lane & 15);
          const int bb = cidx >> 5;
          const int o = cidx & 31;
          out[(((size_t)bb << 12) + n) * 32 + o] = acc[mi][ni][q] + badd;
        }
      }
    }
  }
}

extern "C" void kernel_launch(void* const* d_in, const int* in_sizes, int n_in,
                              void* d_out, int out_size, void* d_ws, size_t ws_size,
                              hipStream_t stream) {
  const float* x = (const float*)d_in[0];
  const float* adj = (const float*)d_in[1];
  const float* W = (const float*)d_in[2];
  const float* bias = (const float*)d_in[3];
  float* out = (float*)d_out;

  const size_t ST_B = (size_t)2048 * 4096 * 2;      // 16,777,216
  const size_t ADJ_FULL = (size_t)4096 * 4096 * 2;  // 33,554,432

  unsigned short* St = (unsigned short*)d_ws;

  if (ws_size >= ST_B + ADJ_FULL) {
    // full path: fused prep + one GEMM (grid 256 = 1 blk/CU, 8 waves)
    unsigned short* adjB = St + (ST_B / 2);
    hipLaunchKernelGGL(k_prep, dim3(9216), dim3(256), 0, stream, x, adj, W, St,
                       adjB);
    hipLaunchKernelGGL(k_gemm8p, dim3(256), dim3(512), 0, stream, adjB, St,
                       bias, out, 4, 0);
  } else {
    // fallback half-split (not expected to run): one 2048-row panel reused
    unsigned short* adjH = St + (ST_B / 2);
    hipLaunchKernelGGL(k_support, dim3((B_SZ * N_SZ) / 256), dim3(256), 0,
                       stream, x, W, St);
    hipLaunchKernelGGL(k_cvt, dim3((2048 * 4096) / 2048), dim3(256), 0, stream,
                       adj, adjH);
    hipLaunchKernelGGL(k_gemm8p, dim3(128), dim3(512), 0, stream, adjH, St,
                       bias, out, 2, 0);
    hipLaunchKernelGGL(k_cvt, dim3((2048 * 4096) / 2048), dim3(256), 0, stream,
                       adj + (size_t)2048 * 4096, adjH);
    hipLaunchKernelGGL(k_gemm8p, dim3(128), dim3(512), 0, stream, adjH, St,
                       bias, out, 2, 2048);
  }
}